// Round 1
// baseline (468.899 us; speedup 1.0000x reference)
//
#include <hip/hip_runtime.h>

typedef unsigned short u16;
typedef unsigned int u32;
typedef __attribute__((ext_vector_type(8))) short short8v;   // 8 x bf16 (raw bits)
typedef __attribute__((ext_vector_type(4))) float f32x4;

#define DD 768
#define PP 1024
#define NTOK 4096

__device__ __forceinline__ u16 f2bf(float f) {
  u32 u = __builtin_bit_cast(u32, f);
  u += 0x7fffu + ((u >> 16) & 1u);
  return (u16)(u >> 16);
}

// ---------------- weight f32 -> bf16 (3 matrices of 589824) ----------------
__global__ __launch_bounds__(256) void cvt_w(const float* __restrict__ a, u16* __restrict__ oa,
                                             const float* __restrict__ b, u16* __restrict__ ob,
                                             const float* __restrict__ c, u16* __restrict__ oc) {
  const int i = blockIdx.x * 256 + threadIdx.x;
  const int m = blockIdx.y;
  const float* s = (m == 0) ? a : (m == 1) ? b : c;
  u16* d = (m == 0) ? oa : (m == 1) ? ob : oc;
  d[i] = f2bf(s[i]);
}

// ---------------- LayerNorm + shortcut copy ----------------
__global__ __launch_bounds__(256) void ln_k(const float* __restrict__ x,
                                            const float* __restrict__ gw, const float* __restrict__ gb,
                                            u16* __restrict__ lnout, float* __restrict__ shortcut) {
  const int tok = blockIdx.x;
  const int t = threadIdx.x;
  const float* xr = x + (size_t)tok * DD;
  float v0 = xr[t], v1 = xr[t + 256], v2 = xr[t + 512];
  float s = v0 + v1 + v2;
  float q = v0 * v0 + v1 * v1 + v2 * v2;
#pragma unroll
  for (int off = 32; off > 0; off >>= 1) {
    s += __shfl_down(s, off, 64);
    q += __shfl_down(q, off, 64);
  }
  __shared__ float ss[4], qs[4];
  const int wid = t >> 6, lane = t & 63;
  if (lane == 0) { ss[wid] = s; qs[wid] = q; }
  __syncthreads();
  const float st = ss[0] + ss[1] + ss[2] + ss[3];
  const float qt = qs[0] + qs[1] + qs[2] + qs[3];
  const float mu = st * (1.f / 768.f);
  const float var = qt * (1.f / 768.f) - mu * mu;
  const float rstd = rsqrtf(var + 1e-5f);
  float* sc = shortcut + (size_t)tok * DD;
  u16* lo = lnout + (size_t)tok * DD;
  sc[t] = v0; sc[t + 256] = v1; sc[t + 512] = v2;
  lo[t]       = f2bf((v0 - mu) * rstd * gw[t] + gb[t]);
  lo[t + 256] = f2bf((v1 - mu) * rstd * gw[t + 256] + gb[t + 256]);
  lo[t + 512] = f2bf((v2 - mu) * rstd * gw[t + 512] + gb[t + 512]);
}

// ---------------- bf16 MFMA GEMM: out[o,pg] = sum_c A[o,c]*Bt[pg,c] ----------------
// A: 768x768 bf16 row-major [o][c];  Bt: 4096x768 bf16 token-major [pg][c]
// mode 0: store f32 channel-major out[(b*768+o)*1024 + p]
// mode 1: store f32 token-major   out[pg*768 + o]
__global__ __launch_bounds__(256) void gemm_bf16(const u16* __restrict__ A,
                                                 const u16* __restrict__ Bt,
                                                 float* __restrict__ out, const int mode) {
  __shared__ u16 Al[64][40];
  __shared__ u16 Bl[128][40];
  const int t = threadIdx.x;
  const int ntile = blockIdx.x * 128;
  const int mtile = blockIdx.y * 64;
  const int wid = t >> 6, lane = t & 63;
  const int m0 = (wid & 1) * 32, n0 = (wid >> 1) * 64;
  const int l15 = lane & 15, quad = lane >> 4;
  f32x4 acc[2][4];
#pragma unroll
  for (int mi = 0; mi < 2; ++mi)
#pragma unroll
    for (int ni = 0; ni < 4; ++ni) acc[mi][ni] = (f32x4){0.f, 0.f, 0.f, 0.f};
  const int ra = t >> 2, sa = t & 3;
  const int rb = t >> 1, hb = t & 1;
  const u16* ag = A + (size_t)(mtile + ra) * DD + sa * 8;
  const u16* bg = Bt + (size_t)(ntile + rb) * DD + hb * 16;
  for (int k0 = 0; k0 < DD; k0 += 32) {
    const uint4 av = *reinterpret_cast<const uint4*>(ag + k0);
    const uint4 bv0 = *reinterpret_cast<const uint4*>(bg + k0);
    const uint4 bv1 = *reinterpret_cast<const uint4*>(bg + k0 + 8);
    __syncthreads();
    *reinterpret_cast<uint4*>(&Al[ra][sa * 8]) = av;
    *reinterpret_cast<uint4*>(&Bl[rb][hb * 16]) = bv0;
    *reinterpret_cast<uint4*>(&Bl[rb][hb * 16 + 8]) = bv1;
    __syncthreads();
    short8v af[2];
#pragma unroll
    for (int mi = 0; mi < 2; ++mi)
      af[mi] = *reinterpret_cast<const short8v*>(&Al[m0 + mi * 16 + l15][quad * 8]);
    short8v bfr[4];
#pragma unroll
    for (int ni = 0; ni < 4; ++ni)
      bfr[ni] = *reinterpret_cast<const short8v*>(&Bl[n0 + ni * 16 + l15][quad * 8]);
#pragma unroll
    for (int mi = 0; mi < 2; ++mi)
#pragma unroll
      for (int ni = 0; ni < 4; ++ni)
        acc[mi][ni] = __builtin_amdgcn_mfma_f32_16x16x32_bf16(af[mi], bfr[ni], acc[mi][ni], 0, 0, 0);
  }
#pragma unroll
  for (int mi = 0; mi < 2; ++mi) {
#pragma unroll
    for (int ni = 0; ni < 4; ++ni) {
      const int ob = mtile + m0 + mi * 16 + quad * 4;
      const int pg = ntile + n0 + ni * 16 + l15;
      if (mode == 0) {
        const int bb = pg >> 10, pq = pg & 1023;
#pragma unroll
        for (int r = 0; r < 4; ++r)
          out[((size_t)(bb * DD + ob + r)) * PP + pq] = acc[mi][ni][r];
      } else {
        *reinterpret_cast<f32x4*>(out + (size_t)pg * DD + ob) = acc[mi][ni];
      }
    }
  }
}

// ---------------- depthwise 7x7 + bias, f32 -> f32 ----------------
__global__ __launch_bounds__(256) void dwconv7_k(const float* __restrict__ x,
                                                 const float* __restrict__ wgt,
                                                 const float* __restrict__ bias,
                                                 float* __restrict__ y) {
  const int bc = blockIdx.x;
  const int c = bc % DD;
  __shared__ float tile[38 * 38];
  __shared__ float wl[49];
  __shared__ float bsh[1];
  const int t = threadIdx.x;
  for (int i = t; i < 38 * 38; i += 256) tile[i] = 0.f;
  __syncthreads();
  const float* xr = x + (size_t)bc * PP;
  for (int i = t; i < 1024; i += 256) tile[((i >> 5) + 3) * 38 + (i & 31) + 3] = xr[i];
  if (t < 49) wl[t] = wgt[c * 49 + t];
  if (t == 0) bsh[0] = bias[c];
  __syncthreads();
  float* yo = y + (size_t)bc * PP;
  for (int i = t; i < 1024; i += 256) {
    const int h = i >> 5, w = i & 31;
    float acc = bsh[0];
#pragma unroll
    for (int kh = 0; kh < 7; ++kh)
#pragma unroll
      for (int kw = 0; kw < 7; ++kw)
        acc = fmaf(wl[kh * 7 + kw], tile[(h + kh) * 38 + (w + kw)], acc);
    yo[i] = acc;
  }
}

// ---------------- depthwise 3x3 (no bias) + x*relu(x), f32 -> bf16 ----------------
__global__ __launch_bounds__(256) void dwconv3_k(const float* __restrict__ x,
                                                 const float* __restrict__ wgt,
                                                 u16* __restrict__ y) {
  const int bc = blockIdx.x;
  const int c = bc % DD;
  __shared__ float tile[34 * 34];
  __shared__ float wl[9];
  const int t = threadIdx.x;
  for (int i = t; i < 34 * 34; i += 256) tile[i] = 0.f;
  __syncthreads();
  const float* xr = x + (size_t)bc * PP;
  for (int i = t; i < 1024; i += 256) tile[((i >> 5) + 1) * 34 + (i & 31) + 1] = xr[i];
  if (t < 9) wl[t] = wgt[c * 9 + t];
  __syncthreads();
  u16* yo = y + (size_t)bc * PP;
  for (int i = t; i < 1024; i += 256) {
    const int h = i >> 5, w = i & 31;
    float acc = 0.f;
#pragma unroll
    for (int kh = 0; kh < 3; ++kh)
#pragma unroll
      for (int kw = 0; kw < 3; ++kw)
        acc = fmaf(wl[kh * 3 + kw], tile[(h + kh) * 34 + (w + kw)], acc);
    const float r = acc > 0.f ? acc * acc : 0.f;
    yo[i] = f2bf(r);
  }
}

// ---------------- xdown: xp[pg][s] = sum_c xdown_w[s,c] * y2[b,c,p] ----------------
__global__ __launch_bounds__(256) void xdown_k(const float* __restrict__ y2,
                                               const float* __restrict__ w,
                                               float* __restrict__ xpo) {
  __shared__ float wl[48][65];
  __shared__ float yl[64][16];
  const int t = threadIdx.x;
  const int p0 = blockIdx.x * 16;
  const int b = p0 >> 10;
  const int pq = p0 & 1023;
  const int px = t & 15, sg = t >> 4;  // sg 0..15, s = sg*3 + {0,1,2}
  float a0 = 0.f, a1 = 0.f, a2 = 0.f;
  for (int c0 = 0; c0 < DD; c0 += 64) {
    __syncthreads();
    for (int i = t; i < 48 * 64; i += 256) { const int s_ = i >> 6, cc = i & 63; wl[s_][cc] = w[s_ * DD + c0 + cc]; }
    for (int i = t; i < 64 * 16; i += 256) { const int cc = i >> 4, pxx = i & 15; yl[cc][pxx] = y2[((size_t)(b * DD + c0 + cc)) * PP + pq + pxx]; }
    __syncthreads();
#pragma unroll 8
    for (int cc = 0; cc < 64; ++cc) {
      const float yv = yl[cc][px];
      a0 = fmaf(wl[sg * 3 + 0][cc], yv, a0);
      a1 = fmaf(wl[sg * 3 + 1][cc], yv, a1);
      a2 = fmaf(wl[sg * 3 + 2][cc], yv, a2);
    }
  }
  float* dst = xpo + (size_t)(p0 + px) * 48 + sg * 3;
  dst[0] = a0; dst[1] = a1; dst[2] = a2;
}

// ---------------- fused gates/coeffs + 4-direction chunked scan + recombine ----------------
// one WG per (b,c). waves 0,1: directions {0,1}; waves 2,3: directions {2,3}.
// lane -> pixel (h = t&31, nc = (t&127)>>5); chunk recurrence along j (w = nc*8+j).
__global__ __launch_bounds__(256) void scan_k(const float* __restrict__ y2,
                                              const float* __restrict__ xp,
                                              const float* __restrict__ wup,
                                              const float* __restrict__ lup,
                                              const float* __restrict__ uup,
                                              const float* __restrict__ dco,
                                              const float* __restrict__ mwp,
                                              u16* __restrict__ out1) {
  const int bc = blockIdx.x;
  const int b = bc / DD;
  const int c = bc - b * DD;
  __shared__ float plane[32][33];
  __shared__ float outp[2][32][33];
  const int t = threadIdx.x;
  {
    const float* yp = y2 + (size_t)bc * PP;
    for (int i = t; i < 1024; i += 256) plane[i >> 5][i & 31] = yp[i];
  }
  const int kk = __builtin_amdgcn_readfirstlane((int)(t >> 7));  // uniform per wave
  const int px = t & 127;
  const int h = px & 31;
  const int nc = px >> 5;
  const int lane = t & 63;
  const int k0 = kk * 2, k1 = kk * 2 + 1;
  const int r0 = k0 * DD + c, r1 = k1 * DD + c;
  const float* wGl0 = wup + (size_t)r0 * 48;
  const float* wGm0 = wup + (size_t)(3072 + r0) * 48;
  const float* wGr0 = wup + (size_t)(6144 + r0) * 48;
  const float* wL0 = lup + (size_t)r0 * 48;
  const float* wU0 = uup + (size_t)r0 * 48;
  const float* wD0 = dco + (size_t)r0 * 48;
  const float* wGl1 = wup + (size_t)r1 * 48;
  const float* wGm1 = wup + (size_t)(3072 + r1) * 48;
  const float* wGr1 = wup + (size_t)(6144 + r1) * 48;
  const float* wL1 = lup + (size_t)r1 * 48;
  const float* wU1 = uup + (size_t)r1 * 48;
  const float* wD1 = dco + (size_t)r1 * 48;
  const float mw0 = mwp[k0], mw1 = mwp[k1];
  float H0 = 0.f, H1 = 0.f;
  const float* xpb = xp + ((size_t)b * 1024 + (size_t)h * 32) * 48;
  __syncthreads();
#pragma unroll 1
  for (int j = 0; j < 8; ++j) {
    const int w = nc * 8 + j;
    const float* xr = xpb + (size_t)w * 48;
    float xpv[48];
#pragma unroll
    for (int q = 0; q < 12; ++q) {
      const float4 vv = reinterpret_cast<const float4*>(xr)[q];
      xpv[4 * q] = vv.x; xpv[4 * q + 1] = vv.y; xpv[4 * q + 2] = vv.z; xpv[4 * q + 3] = vv.w;
    }
    float aGl0 = 0.f, aGm0 = 0.f, aGr0 = 0.f, aL0 = 0.f, aU0 = 0.f, aD0 = 0.f;
    float aGl1 = 0.f, aGm1 = 0.f, aGr1 = 0.f, aL1 = 0.f, aU1 = 0.f, aD1 = 0.f;
#pragma unroll
    for (int s = 0; s < 48; ++s) {
      const float xv = xpv[s];
      aGl0 = fmaf(wGl0[s], xv, aGl0);
      aGm0 = fmaf(wGm0[s], xv, aGm0);
      aGr0 = fmaf(wGr0[s], xv, aGr0);
      aL0 = fmaf(wL0[s], xv, aL0);
      aU0 = fmaf(wU0[s], xv, aU0);
      aD0 = fmaf(wD0[s], xv, aD0);
      aGl1 = fmaf(wGl1[s], xv, aGl1);
      aGm1 = fmaf(wGm1[s], xv, aGm1);
      aGr1 = fmaf(wGr1[s], xv, aGr1);
      aL1 = fmaf(wL1[s], xv, aL1);
      aU1 = fmaf(wU1[s], xv, aU1);
      aD1 = fmaf(wD1[s], xv, aD1);
    }
    float gl0 = 1.f / (1.f + __expf(-aGl0));
    float gm0 = 1.f / (1.f + __expf(-aGm0));
    float gr0 = 1.f / (1.f + __expf(-aGr0));
    float gl1 = 1.f / (1.f + __expf(-aGl1));
    float gm1 = 1.f / (1.f + __expf(-aGm1));
    float gr1 = 1.f / (1.f + __expf(-aGr1));
    float s0 = (h == 0) ? (gm0 + gr0) : ((h == 31) ? (gl0 + gm0) : (gl0 + gm0 + gr0));
    float s1 = (h == 0) ? (gm1 + gr1) : ((h == 31) ? (gl1 + gm1) : (gl1 + gm1 + gr1));
    s0 = fmaxf(s0, 1e-7f); s1 = fmaxf(s1, 1e-7f);
    const float i0 = 1.f / s0, i1 = 1.f / s1;
    gl0 *= i0; gm0 *= i0; gr0 *= i0;
    gl1 *= i1; gm1 *= i1; gr1 *= i1;
    // direction-specific x inputs (k0 in {0,2}, k1 in {1,3})
    const float xv0 = (kk == 0) ? plane[h][w] : plane[h][31 - w];
    const float xv1 = (kk == 0) ? plane[w][h] : plane[31 - w][h];
    float up0 = __shfl(H0, lane - 1, 64);
    float dn0 = __shfl(H0, lane + 1, 64);
    float up1 = __shfl(H1, lane - 1, 64);
    float dn1 = __shfl(H1, lane + 1, 64);
    if (h == 0) { up0 = 0.f; up1 = 0.f; }
    if (h == 31) { dn0 = 0.f; dn1 = 0.f; }
    H0 = aL0 * xv0 + gl0 * up0 + gm0 * H0 + gr0 * dn0;
    H1 = aL1 * xv1 + gl1 * up1 + gm1 * H1 + gr1 * dn1;
    outp[kk][h][w] = mw0 * (H0 * aU0 + xv0 * aD0) + mw1 * (H1 * aU1 + xv1 * aD1);
  }
  __syncthreads();
  u16* dst = out1 + (size_t)bc * PP;
  for (int i = t; i < 1024; i += 256)
    dst[i] = f2bf(outp[0][i >> 5][i & 31] + outp[1][i >> 5][i & 31]);
}

// ---------------- bf16 transpose: [b][c][p] -> [(b*1024+p)][c] ----------------
__global__ __launch_bounds__(256) void transpose_bf16(const u16* __restrict__ in,
                                                      u16* __restrict__ out) {
  __shared__ u16 tile[64][72];
  const int b = blockIdx.z;
  const int c0 = blockIdx.y * 64;
  const int p0 = blockIdx.x * 64;
  const int t = threadIdx.x;
  const int r = t >> 2, s2 = t & 3;
  const u16* src = in + ((size_t)(b * DD + c0 + r)) * PP + p0 + s2 * 16;
  *reinterpret_cast<uint4*>(&tile[r][s2 * 16]) = *reinterpret_cast<const uint4*>(src);
  *reinterpret_cast<uint4*>(&tile[r][s2 * 16 + 8]) = *reinterpret_cast<const uint4*>(src + 8);
  __syncthreads();
  const int pr = t >> 2, cs = t & 3;
  union { u16 u[16]; uint4 v[2]; } vals;
#pragma unroll
  for (int i = 0; i < 16; ++i) vals.u[i] = tile[cs * 16 + i][pr];
  u16* dst = out + ((size_t)(b * 1024 + p0 + pr)) * DD + c0 + cs * 16;
  reinterpret_cast<uint4*>(dst)[0] = vals.v[0];
  reinterpret_cast<uint4*>(dst)[1] = vals.v[1];
}

extern "C" void kernel_launch(void* const* d_in, const int* in_sizes, int n_in,
                              void* d_out, int out_size, void* d_ws, size_t ws_size,
                              hipStream_t stream) {
  const float* hs   = (const float*)d_in[0];
  const float* nw   = (const float*)d_in[1];
  const float* nb   = (const float*)d_in[2];
  const float* win  = (const float*)d_in[3];
  const float* c7w  = (const float*)d_in[4];
  const float* c7b  = (const float*)d_in[5];
  const float* xdw  = (const float*)d_in[6];
  const float* wupw = (const float*)d_in[7];
  const float* lupw = (const float*)d_in[8];
  const float* uupw = (const float*)d_in[9];
  const float* dcow = (const float*)d_in[10];
  const float* mww  = (const float*)d_in[11];
  const float* wout = (const float*)d_in[12];
  const float* odw  = (const float*)d_in[13];
  const float* wprj = (const float*)d_in[14];
  float* out0 = (float*)d_out;
  float* shortcut = out0 + (size_t)NTOK * DD;

  char* ws = (char*)d_ws;
  // lifetimes: A: ln_bf16 (k2..k3) then out1_t (k7..k8). C: y1 (k3..k4) then y3 (k8..k9).
  // D: y2 (k4..k6) then y4_t (k10..k11). F: out1_bf16 (k6..k7) then y4_bf16 (k9..k10).
  u16* lnA    = (u16*)(ws + 0);           // 6,291,456 B
  u16* wInB   = (u16*)(ws + 6291456);     // 1,179,648 B
  u16* wOutB  = (u16*)(ws + 7471104);     // 1,179,648 B
  u16* wPrjB  = (u16*)(ws + 8650752);     // 1,179,648 B
  float* bufC = (float*)(ws + 9830400);   // 12,582,912 B
  float* bufD = (float*)(ws + 22413312);  // 12,582,912 B
  float* xpB  = (float*)(ws + 34996224);  // 786,432 B
  u16* bufF   = (u16*)(ws + 35782656);    // 6,291,456 B  (total 42,074,112 B)
  u16* out1T  = lnA;
  u16* y4T    = (u16*)bufD;

  cvt_w<<<dim3(2304, 3), 256, 0, stream>>>(win, wInB, wout, wOutB, wprj, wPrjB);
  ln_k<<<4096, 256, 0, stream>>>(hs, nw, nb, lnA, shortcut);
  gemm_bf16<<<dim3(32, 12), 256, 0, stream>>>(wInB, lnA, bufC, 0);          // in_proj -> y1 [b][o][p]
  dwconv7_k<<<3072, 256, 0, stream>>>(bufC, c7w, c7b, bufD);                // y2
  xdown_k<<<256, 256, 0, stream>>>(bufD, xdw, xpB);                         // xp [pg][48]
  scan_k<<<3072, 256, 0, stream>>>(bufD, xpB, wupw, lupw, uupw, dcow, mww, bufF);  // out1 bf16 [b][c][p]
  transpose_bf16<<<dim3(16, 12, 4), 256, 0, stream>>>(bufF, out1T);         // -> [pg][c]
  gemm_bf16<<<dim3(32, 12), 256, 0, stream>>>(wOutB, out1T, bufC, 0);       // outconv -> y3 [b][o][p]
  dwconv3_k<<<3072, 256, 0, stream>>>(bufC, odw, bufF);                     // dw3 + x*relu(x) -> bf16
  transpose_bf16<<<dim3(16, 12, 4), 256, 0, stream>>>(bufF, y4T);           // -> [pg][c]
  gemm_bf16<<<dim3(32, 12), 256, 0, stream>>>(wPrjB, y4T, out0, 1);         // outproj -> out [b][t][d]
}

// Round 2
// 344.701 us; speedup vs baseline: 1.3603x; 1.3603x over previous
//
#include <hip/hip_runtime.h>

typedef unsigned short u16;
typedef unsigned int u32;
typedef __attribute__((ext_vector_type(8))) short short8v;   // 8 x bf16 (raw bits)
typedef __attribute__((ext_vector_type(4))) float f32x4;

#define DD 768
#define PP 1024
#define NTOK 4096
#define AS 1032   // act row stride (bf16 elems): 1024 + 8 pad -> ~conflict-free

__device__ __forceinline__ u16 f2bf(float f) {
  u32 u = __builtin_bit_cast(u32, f);
  u += 0x7fffu + ((u >> 16) & 1u);
  return (u16)(u >> 16);
}
__device__ __forceinline__ float b2f(u16 v) {
  return __builtin_bit_cast(float, (u32)v << 16);
}

// ---------------- weight f32 -> bf16 (3 matrices of 589824) ----------------
__global__ __launch_bounds__(256) void cvt_w(const float* __restrict__ a, u16* __restrict__ oa,
                                             const float* __restrict__ b, u16* __restrict__ ob,
                                             const float* __restrict__ c, u16* __restrict__ oc) {
  const int i = blockIdx.x * 256 + threadIdx.x;
  const int m = blockIdx.y;
  const float* s = (m == 0) ? a : (m == 1) ? b : c;
  u16* d = (m == 0) ? oa : (m == 1) ? ob : oc;
  d[i] = f2bf(s[i]);
}

// ---------------- gather scan weights: wB[c][32 rows][64 k] bf16, zero-padded ----------------
// row = type*4 + k ; type in {Gl,Gm,Gr,L,U,D}; rows 24..31 zero, cols 48..63 zero
__global__ __launch_bounds__(256) void wcat_k(const float* __restrict__ wup,
                                              const float* __restrict__ lup,
                                              const float* __restrict__ uup,
                                              const float* __restrict__ dco,
                                              u16* __restrict__ wB) {
  const int c = blockIdx.x;
  const int t = threadIdx.x;
  u16* dst = wB + (size_t)c * 2048;
  for (int i = t; i < 2048; i += 256) {
    const int row = i >> 6, s = i & 63;
    u16 v = 0;
    if (row < 24 && s < 48) {
      const int k = row & 3, type = row >> 2;
      const int ch = k * DD + c;
      const float* src;
      if (type < 3) src = wup + ((size_t)(type * 3072 + ch)) * 48;
      else if (type == 3) src = lup + (size_t)ch * 48;
      else if (type == 4) src = uup + (size_t)ch * 48;
      else src = dco + (size_t)ch * 48;
      v = f2bf(src[s]);
    }
    dst[i] = v;
  }
}

// ---------------- LayerNorm + shortcut copy ----------------
__global__ __launch_bounds__(256) void ln_k(const float* __restrict__ x,
                                            const float* __restrict__ gw, const float* __restrict__ gb,
                                            u16* __restrict__ lnout, float* __restrict__ shortcut) {
  const int tok = blockIdx.x;
  const int t = threadIdx.x;
  const float* xr = x + (size_t)tok * DD;
  float v0 = xr[t], v1 = xr[t + 256], v2 = xr[t + 512];
  float s = v0 + v1 + v2;
  float q = v0 * v0 + v1 * v1 + v2 * v2;
#pragma unroll
  for (int off = 32; off > 0; off >>= 1) {
    s += __shfl_down(s, off, 64);
    q += __shfl_down(q, off, 64);
  }
  __shared__ float ss[4], qs[4];
  const int wid = t >> 6, lane = t & 63;
  if (lane == 0) { ss[wid] = s; qs[wid] = q; }
  __syncthreads();
  const float st = ss[0] + ss[1] + ss[2] + ss[3];
  const float qt = qs[0] + qs[1] + qs[2] + qs[3];
  const float mu = st * (1.f / 768.f);
  const float var = qt * (1.f / 768.f) - mu * mu;
  const float rstd = rsqrtf(var + 1e-5f);
  float* sc = shortcut + (size_t)tok * DD;
  u16* lo = lnout + (size_t)tok * DD;
  sc[t] = v0; sc[t + 256] = v1; sc[t + 512] = v2;
  lo[t]       = f2bf((v0 - mu) * rstd * gw[t] + gb[t]);
  lo[t + 256] = f2bf((v1 - mu) * rstd * gw[t + 256] + gb[t + 256]);
  lo[t + 512] = f2bf((v2 - mu) * rstd * gw[t + 512] + gb[t + 512]);
}

// ---------------- bf16 MFMA GEMM: out[o,pg] = sum_c A[o,c]*Bt[pg,c] ----------------
__global__ __launch_bounds__(256) void gemm_bf16(const u16* __restrict__ A,
                                                 const u16* __restrict__ Bt,
                                                 float* __restrict__ out, const int mode) {
  __shared__ u16 Al[64][40];
  __shared__ u16 Bl[128][40];
  const int t = threadIdx.x;
  const int ntile = blockIdx.x * 128;
  const int mtile = blockIdx.y * 64;
  const int wid = t >> 6, lane = t & 63;
  const int m0 = (wid & 1) * 32, n0 = (wid >> 1) * 64;
  const int l15 = lane & 15, quad = lane >> 4;
  f32x4 acc[2][4];
#pragma unroll
  for (int mi = 0; mi < 2; ++mi)
#pragma unroll
    for (int ni = 0; ni < 4; ++ni) acc[mi][ni] = (f32x4){0.f, 0.f, 0.f, 0.f};
  const int ra = t >> 2, sa = t & 3;
  const int rb = t >> 1, hb = t & 1;
  const u16* ag = A + (size_t)(mtile + ra) * DD + sa * 8;
  const u16* bg = Bt + (size_t)(ntile + rb) * DD + hb * 16;
  for (int k0 = 0; k0 < DD; k0 += 32) {
    const uint4 av = *reinterpret_cast<const uint4*>(ag + k0);
    const uint4 bv0 = *reinterpret_cast<const uint4*>(bg + k0);
    const uint4 bv1 = *reinterpret_cast<const uint4*>(bg + k0 + 8);
    __syncthreads();
    *reinterpret_cast<uint4*>(&Al[ra][sa * 8]) = av;
    *reinterpret_cast<uint4*>(&Bl[rb][hb * 16]) = bv0;
    *reinterpret_cast<uint4*>(&Bl[rb][hb * 16 + 8]) = bv1;
    __syncthreads();
    short8v af[2];
#pragma unroll
    for (int mi = 0; mi < 2; ++mi)
      af[mi] = *reinterpret_cast<const short8v*>(&Al[m0 + mi * 16 + l15][quad * 8]);
    short8v bfr[4];
#pragma unroll
    for (int ni = 0; ni < 4; ++ni)
      bfr[ni] = *reinterpret_cast<const short8v*>(&Bl[n0 + ni * 16 + l15][quad * 8]);
#pragma unroll
    for (int mi = 0; mi < 2; ++mi)
#pragma unroll
      for (int ni = 0; ni < 4; ++ni)
        acc[mi][ni] = __builtin_amdgcn_mfma_f32_16x16x32_bf16(af[mi], bfr[ni], acc[mi][ni], 0, 0, 0);
  }
#pragma unroll
  for (int mi = 0; mi < 2; ++mi) {
#pragma unroll
    for (int ni = 0; ni < 4; ++ni) {
      const int ob = mtile + m0 + mi * 16 + quad * 4;
      const int pg = ntile + n0 + ni * 16 + l15;
      if (mode == 0) {
        const int bb = pg >> 10, pq = pg & 1023;
#pragma unroll
        for (int r = 0; r < 4; ++r)
          out[((size_t)(bb * DD + ob + r)) * PP + pq] = acc[mi][ni][r];
      } else {
        *reinterpret_cast<f32x4*>(out + (size_t)pg * DD + ob) = acc[mi][ni];
      }
    }
  }
}

// ---------------- depthwise 7x7 + bias, f32 -> f32 ----------------
__global__ __launch_bounds__(256) void dwconv7_k(const float* __restrict__ x,
                                                 const float* __restrict__ wgt,
                                                 const float* __restrict__ bias,
                                                 float* __restrict__ y) {
  const int bc = blockIdx.x;
  const int c = bc % DD;
  __shared__ float tile[38 * 38];
  __shared__ float wl[49];
  __shared__ float bsh[1];
  const int t = threadIdx.x;
  for (int i = t; i < 38 * 38; i += 256) tile[i] = 0.f;
  __syncthreads();
  const float* xr = x + (size_t)bc * PP;
  for (int i = t; i < 1024; i += 256) tile[((i >> 5) + 3) * 38 + (i & 31) + 3] = xr[i];
  if (t < 49) wl[t] = wgt[c * 49 + t];
  if (t == 0) bsh[0] = bias[c];
  __syncthreads();
  float* yo = y + (size_t)bc * PP;
  for (int i = t; i < 1024; i += 256) {
    const int h = i >> 5, w = i & 31;
    float acc = bsh[0];
#pragma unroll
    for (int kh = 0; kh < 7; ++kh)
#pragma unroll
      for (int kw = 0; kw < 7; ++kw)
        acc = fmaf(wl[kh * 7 + kw], tile[(h + kh) * 38 + (w + kw)], acc);
    yo[i] = acc;
  }
}

// ---------------- depthwise 3x3 (no bias) + x*relu(x), f32 -> bf16 ----------------
__global__ __launch_bounds__(256) void dwconv3_k(const float* __restrict__ x,
                                                 const float* __restrict__ wgt,
                                                 u16* __restrict__ y) {
  const int bc = blockIdx.x;
  const int c = bc % DD;
  __shared__ float tile[34 * 34];
  __shared__ float wl[9];
  const int t = threadIdx.x;
  for (int i = t; i < 34 * 34; i += 256) tile[i] = 0.f;
  __syncthreads();
  const float* xr = x + (size_t)bc * PP;
  for (int i = t; i < 1024; i += 256) tile[((i >> 5) + 1) * 34 + (i & 31) + 1] = xr[i];
  if (t < 9) wl[t] = wgt[c * 9 + t];
  __syncthreads();
  u16* yo = y + (size_t)bc * PP;
  for (int i = t; i < 1024; i += 256) {
    const int h = i >> 5, w = i & 31;
    float acc = 0.f;
#pragma unroll
    for (int kh = 0; kh < 3; ++kh)
#pragma unroll
      for (int kw = 0; kw < 3; ++kw)
        acc = fmaf(wl[kh * 3 + kw], tile[(h + kh) * 34 + (w + kw)], acc);
    const float r = acc > 0.f ? acc * acc : 0.f;
    yo[i] = f2bf(r);
  }
}

// ---------------- xdown: xpA[b*1024 + q][64] bf16, q = w*32 + h, cols 48..63 zero ----------------
__global__ __launch_bounds__(256) void xdown_k(const float* __restrict__ y2,
                                               const float* __restrict__ w,
                                               u16* __restrict__ xpA) {
  __shared__ float wl[48][65];
  __shared__ float yl[64][16];
  const int t = threadIdx.x;
  const int p0 = blockIdx.x * 16;
  const int b = p0 >> 10;
  const int pq = p0 & 1023;
  const int px = t & 15, sg = t >> 4;  // sg 0..15, s = sg*3 + {0,1,2}
  float a0 = 0.f, a1 = 0.f, a2 = 0.f;
  for (int c0 = 0; c0 < DD; c0 += 64) {
    __syncthreads();
    for (int i = t; i < 48 * 64; i += 256) { const int s_ = i >> 6, cc = i & 63; wl[s_][cc] = w[s_ * DD + c0 + cc]; }
    for (int i = t; i < 64 * 16; i += 256) { const int cc = i >> 4, pxx = i & 15; yl[cc][pxx] = y2[((size_t)(b * DD + c0 + cc)) * PP + pq + pxx]; }
    __syncthreads();
#pragma unroll 8
    for (int cc = 0; cc < 64; ++cc) {
      const float yv = yl[cc][px];
      a0 = fmaf(wl[sg * 3 + 0][cc], yv, a0);
      a1 = fmaf(wl[sg * 3 + 1][cc], yv, a1);
      a2 = fmaf(wl[sg * 3 + 2][cc], yv, a2);
    }
  }
  const int pb = pq + px;                       // in-batch pixel, h-major
  const int q = (pb & 31) * 32 + (pb >> 5);     // q = w*32 + h
  u16* dst = xpA + ((size_t)(b * 1024 + q)) * 64;
  dst[sg * 3 + 0] = f2bf(a0);
  dst[sg * 3 + 1] = f2bf(a1);
  dst[sg * 3 + 2] = f2bf(a2);
  dst[48 + sg] = 0;                             // zero K-pad
}

// ---------------- fused MFMA projections + 4-direction chunked scan + recombine ----------------
// one WG per (b,c). Phase A: MFMA [1024 q x 48] * [48 x 24] -> act bf16 in LDS.
// Phase B: waves 0,1 -> dirs {0,1}; waves 2,3 -> dirs {2,3}; h = lane&31.
__global__ __launch_bounds__(256) void scan_k(const float* __restrict__ y2,
                                              const u16* __restrict__ xpA,
                                              const u16* __restrict__ wB,
                                              const float* __restrict__ mwp,
                                              u16* __restrict__ out1) {
  const int bc = blockIdx.x;
  const int b = bc / DD;
  const int c = bc - b * DD;
  __shared__ u16 act[24 * AS];        // 49,536 B
  __shared__ float plane[32][33];     //  4,224 B
  __shared__ float outp[2][32][33];   //  8,448 B
  const int t = threadIdx.x;
  const int wid = t >> 6, lane = t & 63, l15 = lane & 15, quad = lane >> 4;
  {
    const float* yp = y2 + (size_t)bc * PP;
    for (int i = t; i < 1024; i += 256) plane[i >> 5][i & 31] = yp[i];
  }
  // ---- phase A: projections via MFMA ----
  {
    const u16* wc = wB + (size_t)c * 2048;
    short8v bw[2][2];
#pragma unroll
    for (int nt = 0; nt < 2; ++nt)
#pragma unroll
      for (int ks = 0; ks < 2; ++ks)
        bw[nt][ks] = *reinterpret_cast<const short8v*>(wc + (nt * 16 + l15) * 64 + ks * 32 + quad * 8);
    const u16* ab = xpA + ((size_t)(b * 1024 + wid * 256)) * 64;
#pragma unroll 4
    for (int mt = 0; mt < 16; ++mt) {
      const u16* ar = ab + (mt * 16 + l15) * 64 + quad * 8;
      const short8v a0 = *reinterpret_cast<const short8v*>(ar);
      const short8v a1 = *reinterpret_cast<const short8v*>(ar + 32);
      f32x4 acc0 = {0.f, 0.f, 0.f, 0.f}, acc1 = {0.f, 0.f, 0.f, 0.f};
      acc0 = __builtin_amdgcn_mfma_f32_16x16x32_bf16(a0, bw[0][0], acc0, 0, 0, 0);
      acc0 = __builtin_amdgcn_mfma_f32_16x16x32_bf16(a1, bw[0][1], acc0, 0, 0, 0);
      acc1 = __builtin_amdgcn_mfma_f32_16x16x32_bf16(a0, bw[1][0], acc1, 0, 0, 0);
      acc1 = __builtin_amdgcn_mfma_f32_16x16x32_bf16(a1, bw[1][1], acc1, 0, 0, 0);
      const int qb = wid * 256 + mt * 16 + quad * 4;   // D: row(q) = quad*4+reg, col(coef) = l15
      const u32 lo0 = (u32)f2bf(acc0[0]) | ((u32)f2bf(acc0[1]) << 16);
      const u32 hi0 = (u32)f2bf(acc0[2]) | ((u32)f2bf(acc0[3]) << 16);
      *reinterpret_cast<uint2*>(&act[l15 * AS + qb]) = make_uint2(lo0, hi0);
      if (l15 < 8) {
        const u32 lo1 = (u32)f2bf(acc1[0]) | ((u32)f2bf(acc1[1]) << 16);
        const u32 hi1 = (u32)f2bf(acc1[2]) | ((u32)f2bf(acc1[3]) << 16);
        *reinterpret_cast<uint2*>(&act[(16 + l15) * AS + qb]) = make_uint2(lo1, hi1);
      }
    }
  }
  __syncthreads();
  // ---- phase B: chunked scan ----
  const int kk = __builtin_amdgcn_readfirstlane((int)(t >> 7));  // direction pair, wave-uniform
  const int px = t & 127;
  const int h = px & 31;
  const int nc = px >> 5;
  const int k0 = kk * 2, k1 = k0 + 1;
  const float mw0 = mwp[k0], mw1 = mwp[k1];
  const int rGl0 = (0 + k0) * AS,  rGl1 = (0 + k1) * AS;
  const int rGm0 = (4 + k0) * AS,  rGm1 = (4 + k1) * AS;
  const int rGr0 = (8 + k0) * AS,  rGr1 = (8 + k1) * AS;
  const int rL0  = (12 + k0) * AS, rL1  = (12 + k1) * AS;
  const int rU0  = (16 + k0) * AS, rU1  = (16 + k1) * AS;
  const int rD0  = (20 + k0) * AS, rD1  = (20 + k1) * AS;
  float H0 = 0.f, H1 = 0.f;
#pragma unroll 1
  for (int j = 0; j < 8; ++j) {
    const int w = nc * 8 + j;
    const int qj = w * 32 + h;
    const float aGl0 = b2f(act[rGl0 + qj]), aGl1 = b2f(act[rGl1 + qj]);
    const float aGm0 = b2f(act[rGm0 + qj]), aGm1 = b2f(act[rGm1 + qj]);
    const float aGr0 = b2f(act[rGr0 + qj]), aGr1 = b2f(act[rGr1 + qj]);
    const float aL0  = b2f(act[rL0 + qj]),  aL1  = b2f(act[rL1 + qj]);
    const float aU0  = b2f(act[rU0 + qj]),  aU1  = b2f(act[rU1 + qj]);
    const float aD0  = b2f(act[rD0 + qj]),  aD1  = b2f(act[rD1 + qj]);
    float gl0 = 1.f / (1.f + __expf(-aGl0));
    float gm0 = 1.f / (1.f + __expf(-aGm0));
    float gr0 = 1.f / (1.f + __expf(-aGr0));
    float gl1 = 1.f / (1.f + __expf(-aGl1));
    float gm1 = 1.f / (1.f + __expf(-aGm1));
    float gr1 = 1.f / (1.f + __expf(-aGr1));
    float s0 = (h == 0) ? (gm0 + gr0) : ((h == 31) ? (gl0 + gm0) : (gl0 + gm0 + gr0));
    float s1 = (h == 0) ? (gm1 + gr1) : ((h == 31) ? (gl1 + gm1) : (gl1 + gm1 + gr1));
    s0 = fmaxf(s0, 1e-7f); s1 = fmaxf(s1, 1e-7f);
    const float i0 = 1.f / s0, i1 = 1.f / s1;
    gl0 *= i0; gm0 *= i0; gr0 *= i0;
    gl1 *= i1; gm1 *= i1; gr1 *= i1;
    const float xv0 = (kk == 0) ? plane[h][w] : plane[h][31 - w];
    const float xv1 = (kk == 0) ? plane[w][h] : plane[31 - w][h];
    float up0 = __shfl(H0, lane - 1, 64);
    float dn0 = __shfl(H0, lane + 1, 64);
    float up1 = __shfl(H1, lane - 1, 64);
    float dn1 = __shfl(H1, lane + 1, 64);
    if (h == 0) { up0 = 0.f; up1 = 0.f; }
    if (h == 31) { dn0 = 0.f; dn1 = 0.f; }
    H0 = aL0 * xv0 + gl0 * up0 + gm0 * H0 + gr0 * dn0;
    H1 = aL1 * xv1 + gl1 * up1 + gm1 * H1 + gr1 * dn1;
    outp[kk][h][w] = mw0 * (H0 * aU0 + xv0 * aD0) + mw1 * (H1 * aU1 + xv1 * aD1);
  }
  __syncthreads();
  u16* dst = out1 + (size_t)bc * PP;
  for (int i = t; i < 1024; i += 256)
    dst[i] = f2bf(outp[0][i >> 5][i & 31] + outp[1][i >> 5][i & 31]);
}

// ---------------- bf16 transpose: [b][c][p] -> [(b*1024+p)][c] ----------------
__global__ __launch_bounds__(256) void transpose_bf16(const u16* __restrict__ in,
                                                      u16* __restrict__ out) {
  __shared__ u16 tile[64][72];
  const int b = blockIdx.z;
  const int c0 = blockIdx.y * 64;
  const int p0 = blockIdx.x * 64;
  const int t = threadIdx.x;
  const int r = t >> 2, s2 = t & 3;
  const u16* src = in + ((size_t)(b * DD + c0 + r)) * PP + p0 + s2 * 16;
  *reinterpret_cast<uint4*>(&tile[r][s2 * 16]) = *reinterpret_cast<const uint4*>(src);
  *reinterpret_cast<uint4*>(&tile[r][s2 * 16 + 8]) = *reinterpret_cast<const uint4*>(src + 8);
  __syncthreads();
  const int pr = t >> 2, cs = t & 3;
  union { u16 u[16]; uint4 v[2]; } vals;
#pragma unroll
  for (int i = 0; i < 16; ++i) vals.u[i] = tile[cs * 16 + i][pr];
  u16* dst = out + ((size_t)(b * 1024 + p0 + pr)) * DD + c0 + cs * 16;
  reinterpret_cast<uint4*>(dst)[0] = vals.v[0];
  reinterpret_cast<uint4*>(dst)[1] = vals.v[1];
}

extern "C" void kernel_launch(void* const* d_in, const int* in_sizes, int n_in,
                              void* d_out, int out_size, void* d_ws, size_t ws_size,
                              hipStream_t stream) {
  const float* hs   = (const float*)d_in[0];
  const float* nw   = (const float*)d_in[1];
  const float* nb   = (const float*)d_in[2];
  const float* win  = (const float*)d_in[3];
  const float* c7w  = (const float*)d_in[4];
  const float* c7b  = (const float*)d_in[5];
  const float* xdw  = (const float*)d_in[6];
  const float* wupw = (const float*)d_in[7];
  const float* lupw = (const float*)d_in[8];
  const float* uupw = (const float*)d_in[9];
  const float* dcow = (const float*)d_in[10];
  const float* mww  = (const float*)d_in[11];
  const float* wout = (const float*)d_in[12];
  const float* odw  = (const float*)d_in[13];
  const float* wprj = (const float*)d_in[14];
  float* out0 = (float*)d_out;
  float* shortcut = out0 + (size_t)NTOK * DD;

  char* ws = (char*)d_ws;
  // lifetimes: A: ln_bf16 (ln..gemm1) then out1_t. C: y1 (gemm1..dw7), then {xpA,wB} (wcat..scan), then y3.
  // D: y2 (dw7..scan) then y4_t. F: out1_bf16 then y4_bf16.
  u16* lnA    = (u16*)(ws + 0);           // 6,291,456 B
  u16* wInB   = (u16*)(ws + 6291456);     // 1,179,648 B
  u16* wOutB  = (u16*)(ws + 7471104);     // 1,179,648 B
  u16* wPrjB  = (u16*)(ws + 8650752);     // 1,179,648 B
  float* bufC = (float*)(ws + 9830400);   // 12,582,912 B
  float* bufD = (float*)(ws + 22413312);  // 12,582,912 B
  u16* bufF   = (u16*)(ws + 35782656);    // 6,291,456 B  (total 42,074,112 B)
  u16* xpA    = (u16*)bufC;               // 524,288 B   (aliases y1 slot, after dwconv7)
  u16* wB     = (u16*)((char*)bufC + 524288);  // 3,145,728 B
  u16* out1T  = lnA;
  u16* y4T    = (u16*)bufD;

  cvt_w<<<dim3(2304, 3), 256, 0, stream>>>(win, wInB, wout, wOutB, wprj, wPrjB);
  ln_k<<<4096, 256, 0, stream>>>(hs, nw, nb, lnA, shortcut);
  gemm_bf16<<<dim3(32, 12), 256, 0, stream>>>(wInB, lnA, bufC, 0);          // in_proj -> y1 [b][o][p]
  dwconv7_k<<<3072, 256, 0, stream>>>(bufC, c7w, c7b, bufD);                // y2
  wcat_k<<<768, 256, 0, stream>>>(wupw, lupw, uupw, dcow, wB);              // gathered scan weights (bf16)
  xdown_k<<<256, 256, 0, stream>>>(bufD, xdw, xpA);                         // xp bf16, q-ordered, K-padded
  scan_k<<<3072, 256, 0, stream>>>(bufD, xpA, wB, mww, bufF);               // out1 bf16 [b][c][p]
  transpose_bf16<<<dim3(16, 12, 4), 256, 0, stream>>>(bufF, out1T);         // -> [pg][c]
  gemm_bf16<<<dim3(32, 12), 256, 0, stream>>>(wOutB, out1T, bufC, 0);       // outconv -> y3 [b][o][p]
  dwconv3_k<<<3072, 256, 0, stream>>>(bufC, odw, bufF);                     // dw3 + x*relu(x) -> bf16
  transpose_bf16<<<dim3(16, 12, 4), 256, 0, stream>>>(bufF, y4T);           // -> [pg][c]
  gemm_bf16<<<dim3(32, 12), 256, 0, stream>>>(wPrjB, y4T, out0, 1);         // outproj -> out [b][t][d]
}

// Round 3
// 290.338 us; speedup vs baseline: 1.6150x; 1.1872x over previous
//
#include <hip/hip_runtime.h>

typedef unsigned short u16;
typedef unsigned int u32;
typedef __attribute__((ext_vector_type(8))) short short8v;   // 8 x bf16 (raw bits)
typedef __attribute__((ext_vector_type(4))) float f32x4;

#define DD 768
#define PP 1024
#define NTOK 4096
#define AS 1032   // act row stride (bf16 elems): 1024 + 8 pad -> ~conflict-free

__device__ __forceinline__ u16 f2bf(float f) {
  u32 u = __builtin_bit_cast(u32, f);
  u += 0x7fffu + ((u >> 16) & 1u);
  return (u16)(u >> 16);
}
__device__ __forceinline__ float b2f(u16 v) {
  return __builtin_bit_cast(float, (u32)v << 16);
}

// ---------------- weight f32 -> bf16 (3 matrices of 589824) ----------------
__global__ __launch_bounds__(256) void cvt_w(const float* __restrict__ a, u16* __restrict__ oa,
                                             const float* __restrict__ b, u16* __restrict__ ob,
                                             const float* __restrict__ c, u16* __restrict__ oc) {
  const int i = blockIdx.x * 256 + threadIdx.x;
  const int m = blockIdx.y;
  const float* s = (m == 0) ? a : (m == 1) ? b : c;
  u16* d = (m == 0) ? oa : (m == 1) ? ob : oc;
  d[i] = f2bf(s[i]);
}

// ---------------- xdown weight -> bf16, padded 48x768 -> 64x768 (rows 48+ zero) ----------------
__global__ __launch_bounds__(256) void cvt_xd(const float* __restrict__ w, u16* __restrict__ o) {
  const int i = blockIdx.x * 256 + threadIdx.x;   // 64*768 = 49152
  const int r = i / DD;
  o[i] = (r < 48) ? f2bf(w[i]) : (u16)0;
}

// ---------------- gather scan weights: wB[c][32 rows][64 k] bf16, zero-padded ----------------
// row = type*4 + k ; type in {Gl,Gm,Gr,L,U,D}; rows 24..31 zero, cols 48..63 zero
__global__ __launch_bounds__(256) void wcat_k(const float* __restrict__ wup,
                                              const float* __restrict__ lup,
                                              const float* __restrict__ uup,
                                              const float* __restrict__ dco,
                                              u16* __restrict__ wB) {
  const int c = blockIdx.x;
  const int t = threadIdx.x;
  u16* dst = wB + (size_t)c * 2048;
  for (int i = t; i < 2048; i += 256) {
    const int row = i >> 6, s = i & 63;
    u16 v = 0;
    if (row < 24 && s < 48) {
      const int k = row & 3, type = row >> 2;
      const int ch = k * DD + c;
      const float* src;
      if (type < 3) src = wup + ((size_t)(type * 3072 + ch)) * 48;
      else if (type == 3) src = lup + (size_t)ch * 48;
      else if (type == 4) src = uup + (size_t)ch * 48;
      else src = dco + (size_t)ch * 48;
      v = f2bf(src[s]);
    }
    dst[i] = v;
  }
}

// ---------------- LayerNorm + shortcut copy ----------------
__global__ __launch_bounds__(256) void ln_k(const float* __restrict__ x,
                                            const float* __restrict__ gw, const float* __restrict__ gb,
                                            u16* __restrict__ lnout, float* __restrict__ shortcut) {
  const int tok = blockIdx.x;
  const int t = threadIdx.x;
  const float* xr = x + (size_t)tok * DD;
  float v0 = xr[t], v1 = xr[t + 256], v2 = xr[t + 512];
  float s = v0 + v1 + v2;
  float q = v0 * v0 + v1 * v1 + v2 * v2;
#pragma unroll
  for (int off = 32; off > 0; off >>= 1) {
    s += __shfl_down(s, off, 64);
    q += __shfl_down(q, off, 64);
  }
  __shared__ float ss[4], qs[4];
  const int wid = t >> 6, lane = t & 63;
  if (lane == 0) { ss[wid] = s; qs[wid] = q; }
  __syncthreads();
  const float st = ss[0] + ss[1] + ss[2] + ss[3];
  const float qt = qs[0] + qs[1] + qs[2] + qs[3];
  const float mu = st * (1.f / 768.f);
  const float var = qt * (1.f / 768.f) - mu * mu;
  const float rstd = rsqrtf(var + 1e-5f);
  float* sc = shortcut + (size_t)tok * DD;
  u16* lo = lnout + (size_t)tok * DD;
  sc[t] = v0; sc[t + 256] = v1; sc[t + 512] = v2;
  lo[t]       = f2bf((v0 - mu) * rstd * gw[t] + gb[t]);
  lo[t + 256] = f2bf((v1 - mu) * rstd * gw[t + 256] + gb[t + 256]);
  lo[t + 512] = f2bf((v2 - mu) * rstd * gw[t + 512] + gb[t + 512]);
}

// ---------------- bf16 MFMA GEMM: out[o,pg] = sum_c A[o,c]*Bt[pg,c] ----------------
// A: [M x 768] bf16 row-major;  Bt: 4096x768 bf16 token-major
// mode 0: store f32 channel-major out[(b*768+o)*1024 + p]
// mode 1: store f32 token-major   out[pg*768 + o]
// mode 2: store bf16 to xpA[(b*1024 + q)*64 + o], q = (p&31)*32 + (p>>5)
__global__ __launch_bounds__(256) void gemm_bf16(const u16* __restrict__ A,
                                                 const u16* __restrict__ Bt,
                                                 float* __restrict__ out, const int mode) {
  __shared__ u16 Al[64][40];
  __shared__ u16 Bl[128][40];
  const int t = threadIdx.x;
  const int ntile = blockIdx.x * 128;
  const int mtile = blockIdx.y * 64;
  const int wid = t >> 6, lane = t & 63;
  const int m0 = (wid & 1) * 32, n0 = (wid >> 1) * 64;
  const int l15 = lane & 15, quad = lane >> 4;
  f32x4 acc[2][4];
#pragma unroll
  for (int mi = 0; mi < 2; ++mi)
#pragma unroll
    for (int ni = 0; ni < 4; ++ni) acc[mi][ni] = (f32x4){0.f, 0.f, 0.f, 0.f};
  const int ra = t >> 2, sa = t & 3;
  const int rb = t >> 1, hb = t & 1;
  const u16* ag = A + (size_t)(mtile + ra) * DD + sa * 8;
  const u16* bg = Bt + (size_t)(ntile + rb) * DD + hb * 16;
  for (int k0 = 0; k0 < DD; k0 += 32) {
    const uint4 av = *reinterpret_cast<const uint4*>(ag + k0);
    const uint4 bv0 = *reinterpret_cast<const uint4*>(bg + k0);
    const uint4 bv1 = *reinterpret_cast<const uint4*>(bg + k0 + 8);
    __syncthreads();
    *reinterpret_cast<uint4*>(&Al[ra][sa * 8]) = av;
    *reinterpret_cast<uint4*>(&Bl[rb][hb * 16]) = bv0;
    *reinterpret_cast<uint4*>(&Bl[rb][hb * 16 + 8]) = bv1;
    __syncthreads();
    short8v af[2];
#pragma unroll
    for (int mi = 0; mi < 2; ++mi)
      af[mi] = *reinterpret_cast<const short8v*>(&Al[m0 + mi * 16 + l15][quad * 8]);
    short8v bfr[4];
#pragma unroll
    for (int ni = 0; ni < 4; ++ni)
      bfr[ni] = *reinterpret_cast<const short8v*>(&Bl[n0 + ni * 16 + l15][quad * 8]);
#pragma unroll
    for (int mi = 0; mi < 2; ++mi)
#pragma unroll
      for (int ni = 0; ni < 4; ++ni)
        acc[mi][ni] = __builtin_amdgcn_mfma_f32_16x16x32_bf16(af[mi], bfr[ni], acc[mi][ni], 0, 0, 0);
  }
#pragma unroll
  for (int mi = 0; mi < 2; ++mi) {
#pragma unroll
    for (int ni = 0; ni < 4; ++ni) {
      const int ob = mtile + m0 + mi * 16 + quad * 4;
      const int pg = ntile + n0 + ni * 16 + l15;
      if (mode == 0) {
        const int bb = pg >> 10, pq = pg & 1023;
#pragma unroll
        for (int r = 0; r < 4; ++r)
          out[((size_t)(bb * DD + ob + r)) * PP + pq] = acc[mi][ni][r];
      } else if (mode == 1) {
        *reinterpret_cast<f32x4*>(out + (size_t)pg * DD + ob) = acc[mi][ni];
      } else {
        const int bb = pg >> 10, pq = pg & 1023;
        const int q = (pq & 31) * 32 + (pq >> 5);
        u16* dst = (u16*)out + ((size_t)(bb * 1024 + q)) * 64 + ob;
        const u32 lo = (u32)f2bf(acc[mi][ni][0]) | ((u32)f2bf(acc[mi][ni][1]) << 16);
        const u32 hi = (u32)f2bf(acc[mi][ni][2]) | ((u32)f2bf(acc[mi][ni][3]) << 16);
        *reinterpret_cast<uint2*>(dst) = make_uint2(lo, hi);
      }
    }
  }
}

// ---------------- depthwise 7x7 + bias, f32 -> f32 ----------------
__global__ __launch_bounds__(256) void dwconv7_k(const float* __restrict__ x,
                                                 const float* __restrict__ wgt,
                                                 const float* __restrict__ bias,
                                                 float* __restrict__ y) {
  const int bc = blockIdx.x;
  const int c = bc % DD;
  __shared__ float tile[38 * 38];
  __shared__ float wl[49];
  __shared__ float bsh[1];
  const int t = threadIdx.x;
  for (int i = t; i < 38 * 38; i += 256) tile[i] = 0.f;
  __syncthreads();
  const float* xr = x + (size_t)bc * PP;
  for (int i = t; i < 1024; i += 256) tile[((i >> 5) + 3) * 38 + (i & 31) + 3] = xr[i];
  if (t < 49) wl[t] = wgt[c * 49 + t];
  if (t == 0) bsh[0] = bias[c];
  __syncthreads();
  float* yo = y + (size_t)bc * PP;
  for (int i = t; i < 1024; i += 256) {
    const int h = i >> 5, w = i & 31;
    float acc = bsh[0];
#pragma unroll
    for (int kh = 0; kh < 7; ++kh)
#pragma unroll
      for (int kw = 0; kw < 7; ++kw)
        acc = fmaf(wl[kh * 7 + kw], tile[(h + kh) * 38 + (w + kw)], acc);
    yo[i] = acc;
  }
}

// ---------------- depthwise 3x3 (no bias) + x*relu(x), f32 -> bf16 ----------------
__global__ __launch_bounds__(256) void dwconv3_k(const float* __restrict__ x,
                                                 const float* __restrict__ wgt,
                                                 u16* __restrict__ y) {
  const int bc = blockIdx.x;
  const int c = bc % DD;
  __shared__ float tile[34 * 34];
  __shared__ float wl[9];
  const int t = threadIdx.x;
  for (int i = t; i < 34 * 34; i += 256) tile[i] = 0.f;
  __syncthreads();
  const float* xr = x + (size_t)bc * PP;
  for (int i = t; i < 1024; i += 256) tile[((i >> 5) + 1) * 34 + (i & 31) + 1] = xr[i];
  if (t < 9) wl[t] = wgt[c * 9 + t];
  __syncthreads();
  u16* yo = y + (size_t)bc * PP;
  for (int i = t; i < 1024; i += 256) {
    const int h = i >> 5, w = i & 31;
    float acc = 0.f;
#pragma unroll
    for (int kh = 0; kh < 3; ++kh)
#pragma unroll
      for (int kw = 0; kw < 3; ++kw)
        acc = fmaf(wl[kh * 3 + kw], tile[(h + kh) * 34 + (w + kw)], acc);
    const float r = acc > 0.f ? acc * acc : 0.f;
    yo[i] = f2bf(r);
  }
}

// ---------------- fused MFMA projections + 4-direction chunked scan + recombine ----------------
// one WG per (b,c). Phase A: MFMA [1024 q x 48] * [48 x 24] -> act bf16 in LDS.
// Phase B: waves 0,1 -> dirs {0,1}; waves 2,3 -> dirs {2,3}; h = lane&31.
__global__ __launch_bounds__(256) void scan_k(const float* __restrict__ y2,
                                              const u16* __restrict__ xpA,
                                              const u16* __restrict__ wB,
                                              const float* __restrict__ mwp,
                                              u16* __restrict__ out1) {
  const int bc = blockIdx.x;
  const int b = bc / DD;
  const int c = bc - b * DD;
  __shared__ u16 act[24 * AS];        // 49,536 B
  __shared__ float plane[32][33];     //  4,224 B
  __shared__ float outp[2][32][33];   //  8,448 B
  const int t = threadIdx.x;
  const int wid = t >> 6, lane = t & 63, l15 = lane & 15, quad = lane >> 4;
  {
    const float* yp = y2 + (size_t)bc * PP;
    for (int i = t; i < 1024; i += 256) plane[i >> 5][i & 31] = yp[i];
  }
  // ---- phase A: projections via MFMA ----
  {
    const u16* wc = wB + (size_t)c * 2048;
    short8v bw[2][2];
#pragma unroll
    for (int nt = 0; nt < 2; ++nt)
#pragma unroll
      for (int ks = 0; ks < 2; ++ks)
        bw[nt][ks] = *reinterpret_cast<const short8v*>(wc + (nt * 16 + l15) * 64 + ks * 32 + quad * 8);
    const u16* ab = xpA + ((size_t)(b * 1024 + wid * 256)) * 64;
#pragma unroll 4
    for (int mt = 0; mt < 16; ++mt) {
      const u16* ar = ab + (mt * 16 + l15) * 64 + quad * 8;
      const short8v a0 = *reinterpret_cast<const short8v*>(ar);
      const short8v a1 = *reinterpret_cast<const short8v*>(ar + 32);
      f32x4 acc0 = {0.f, 0.f, 0.f, 0.f}, acc1 = {0.f, 0.f, 0.f, 0.f};
      acc0 = __builtin_amdgcn_mfma_f32_16x16x32_bf16(a0, bw[0][0], acc0, 0, 0, 0);
      acc0 = __builtin_amdgcn_mfma_f32_16x16x32_bf16(a1, bw[0][1], acc0, 0, 0, 0);
      acc1 = __builtin_amdgcn_mfma_f32_16x16x32_bf16(a0, bw[1][0], acc1, 0, 0, 0);
      acc1 = __builtin_amdgcn_mfma_f32_16x16x32_bf16(a1, bw[1][1], acc1, 0, 0, 0);
      const int qb = wid * 256 + mt * 16 + quad * 4;   // D: row(q) = quad*4+reg, col(coef) = l15
      const u32 lo0 = (u32)f2bf(acc0[0]) | ((u32)f2bf(acc0[1]) << 16);
      const u32 hi0 = (u32)f2bf(acc0[2]) | ((u32)f2bf(acc0[3]) << 16);
      *reinterpret_cast<uint2*>(&act[l15 * AS + qb]) = make_uint2(lo0, hi0);
      if (l15 < 8) {
        const u32 lo1 = (u32)f2bf(acc1[0]) | ((u32)f2bf(acc1[1]) << 16);
        const u32 hi1 = (u32)f2bf(acc1[2]) | ((u32)f2bf(acc1[3]) << 16);
        *reinterpret_cast<uint2*>(&act[(16 + l15) * AS + qb]) = make_uint2(lo1, hi1);
      }
    }
  }
  __syncthreads();
  // ---- phase B: chunked scan ----
  const int kk = __builtin_amdgcn_readfirstlane((int)(t >> 7));  // direction pair, wave-uniform
  const int px = t & 127;
  const int h = px & 31;
  const int nc = px >> 5;
  const int k0 = kk * 2, k1 = k0 + 1;
  const float mw0 = mwp[k0], mw1 = mwp[k1];
  const int rGl0 = (0 + k0) * AS,  rGl1 = (0 + k1) * AS;
  const int rGm0 = (4 + k0) * AS,  rGm1 = (4 + k1) * AS;
  const int rGr0 = (8 + k0) * AS,  rGr1 = (8 + k1) * AS;
  const int rL0  = (12 + k0) * AS, rL1  = (12 + k1) * AS;
  const int rU0  = (16 + k0) * AS, rU1  = (16 + k1) * AS;
  const int rD0  = (20 + k0) * AS, rD1  = (20 + k1) * AS;
  float H0 = 0.f, H1 = 0.f;
#pragma unroll 1
  for (int j = 0; j < 8; ++j) {
    const int w = nc * 8 + j;
    const int qj = w * 32 + h;
    const float aGl0 = b2f(act[rGl0 + qj]), aGl1 = b2f(act[rGl1 + qj]);
    const float aGm0 = b2f(act[rGm0 + qj]), aGm1 = b2f(act[rGm1 + qj]);
    const float aGr0 = b2f(act[rGr0 + qj]), aGr1 = b2f(act[rGr1 + qj]);
    const float aL0  = b2f(act[rL0 + qj]),  aL1  = b2f(act[rL1 + qj]);
    const float aU0  = b2f(act[rU0 + qj]),  aU1  = b2f(act[rU1 + qj]);
    const float aD0  = b2f(act[rD0 + qj]),  aD1  = b2f(act[rD1 + qj]);
    float gl0 = 1.f / (1.f + __expf(-aGl0));
    float gm0 = 1.f / (1.f + __expf(-aGm0));
    float gr0 = 1.f / (1.f + __expf(-aGr0));
    float gl1 = 1.f / (1.f + __expf(-aGl1));
    float gm1 = 1.f / (1.f + __expf(-aGm1));
    float gr1 = 1.f / (1.f + __expf(-aGr1));
    float s0 = (h == 0) ? (gm0 + gr0) : ((h == 31) ? (gl0 + gm0) : (gl0 + gm0 + gr0));
    float s1 = (h == 0) ? (gm1 + gr1) : ((h == 31) ? (gl1 + gm1) : (gl1 + gm1 + gr1));
    s0 = fmaxf(s0, 1e-7f); s1 = fmaxf(s1, 1e-7f);
    const float i0 = 1.f / s0, i1 = 1.f / s1;
    gl0 *= i0; gm0 *= i0; gr0 *= i0;
    gl1 *= i1; gm1 *= i1; gr1 *= i1;
    const float xv0 = (kk == 0) ? plane[h][w] : plane[h][31 - w];
    const float xv1 = (kk == 0) ? plane[w][h] : plane[31 - w][h];
    float up0 = __shfl(H0, lane - 1, 64);
    float dn0 = __shfl(H0, lane + 1, 64);
    float up1 = __shfl(H1, lane - 1, 64);
    float dn1 = __shfl(H1, lane + 1, 64);
    if (h == 0) { up0 = 0.f; up1 = 0.f; }
    if (h == 31) { dn0 = 0.f; dn1 = 0.f; }
    H0 = aL0 * xv0 + gl0 * up0 + gm0 * H0 + gr0 * dn0;
    H1 = aL1 * xv1 + gl1 * up1 + gm1 * H1 + gr1 * dn1;
    outp[kk][h][w] = mw0 * (H0 * aU0 + xv0 * aD0) + mw1 * (H1 * aU1 + xv1 * aD1);
  }
  __syncthreads();
  u16* dst = out1 + (size_t)bc * PP;
  for (int i = t; i < 1024; i += 256)
    dst[i] = f2bf(outp[0][i >> 5][i & 31] + outp[1][i >> 5][i & 31]);
}

// ---------------- bf16 transpose: [b][c][p] -> [(b*1024+p)][c] ----------------
__global__ __launch_bounds__(256) void transpose_bf16(const u16* __restrict__ in,
                                                      u16* __restrict__ out) {
  __shared__ u16 tile[64][72];
  const int b = blockIdx.z;
  const int c0 = blockIdx.y * 64;
  const int p0 = blockIdx.x * 64;
  const int t = threadIdx.x;
  const int r = t >> 2, s2 = t & 3;
  const u16* src = in + ((size_t)(b * DD + c0 + r)) * PP + p0 + s2 * 16;
  *reinterpret_cast<uint4*>(&tile[r][s2 * 16]) = *reinterpret_cast<const uint4*>(src);
  *reinterpret_cast<uint4*>(&tile[r][s2 * 16 + 8]) = *reinterpret_cast<const uint4*>(src + 8);
  __syncthreads();
  const int pr = t >> 2, cs = t & 3;
  union { u16 u[16]; uint4 v[2]; } vals;
#pragma unroll
  for (int i = 0; i < 16; ++i) vals.u[i] = tile[cs * 16 + i][pr];
  u16* dst = out + ((size_t)(b * 1024 + p0 + pr)) * DD + c0 + cs * 16;
  reinterpret_cast<uint4*>(dst)[0] = vals.v[0];
  reinterpret_cast<uint4*>(dst)[1] = vals.v[1];
}

// ---------------- f32 [b][c][p] -> bf16 token-major [(b*1024+p)][c] ----------------
__global__ __launch_bounds__(256) void transpose_f2b(const float* __restrict__ in,
                                                     u16* __restrict__ out) {
  __shared__ u16 tile[64][72];
  const int b = blockIdx.z;
  const int c0 = blockIdx.y * 64;
  const int p0 = blockIdx.x * 64;
  const int t = threadIdx.x;
  const int r = t >> 2, s2 = t & 3;
  const float* src = in + ((size_t)(b * DD + c0 + r)) * PP + p0 + s2 * 16;
  u16* td = &tile[r][s2 * 16];
#pragma unroll
  for (int q = 0; q < 4; ++q) {
    const float4 v = reinterpret_cast<const float4*>(src)[q];
    td[q * 4 + 0] = f2bf(v.x); td[q * 4 + 1] = f2bf(v.y);
    td[q * 4 + 2] = f2bf(v.z); td[q * 4 + 3] = f2bf(v.w);
  }
  __syncthreads();
  const int pr = t >> 2, cs = t & 3;
  union { u16 u[16]; uint4 v[2]; } vals;
#pragma unroll
  for (int i = 0; i < 16; ++i) vals.u[i] = tile[cs * 16 + i][pr];
  u16* dst = out + ((size_t)(b * 1024 + p0 + pr)) * DD + c0 + cs * 16;
  reinterpret_cast<uint4*>(dst)[0] = vals.v[0];
  reinterpret_cast<uint4*>(dst)[1] = vals.v[1];
}

extern "C" void kernel_launch(void* const* d_in, const int* in_sizes, int n_in,
                              void* d_out, int out_size, void* d_ws, size_t ws_size,
                              hipStream_t stream) {
  const float* hs   = (const float*)d_in[0];
  const float* nw   = (const float*)d_in[1];
  const float* nb   = (const float*)d_in[2];
  const float* win  = (const float*)d_in[3];
  const float* c7w  = (const float*)d_in[4];
  const float* c7b  = (const float*)d_in[5];
  const float* xdw  = (const float*)d_in[6];
  const float* wupw = (const float*)d_in[7];
  const float* lupw = (const float*)d_in[8];
  const float* uupw = (const float*)d_in[9];
  const float* dcow = (const float*)d_in[10];
  const float* mww  = (const float*)d_in[11];
  const float* wout = (const float*)d_in[12];
  const float* odw  = (const float*)d_in[13];
  const float* wprj = (const float*)d_in[14];
  float* out0 = (float*)d_out;
  float* shortcut = out0 + (size_t)NTOK * DD;

  char* ws = (char*)d_ws;
  // Slots: A: ln_bf16 (ln..gemm1) then out1_t. C: y1 (gemm1..dw7), then {xpA,wB,wXdB} (..scan), then y3.
  // D: y2 (dw7..scan) then y4_t. F: y2t (transpose_f2b..xdown_gemm) then out1_bf16 then y4_bf16.
  u16* lnA    = (u16*)(ws + 0);           // 6,291,456 B
  u16* wInB   = (u16*)(ws + 6291456);     // 1,179,648 B
  u16* wOutB  = (u16*)(ws + 7471104);     // 1,179,648 B
  u16* wPrjB  = (u16*)(ws + 8650752);     // 1,179,648 B
  float* bufC = (float*)(ws + 9830400);   // 12,582,912 B
  float* bufD = (float*)(ws + 22413312);  // 12,582,912 B
  u16* bufF   = (u16*)(ws + 35782656);    // 6,291,456 B  (total 42,074,112 B)
  u16* xpA    = (u16*)bufC;               // 524,288 B   (alias y1 slot, valid after dwconv7)
  u16* wB     = (u16*)((char*)bufC + 524288);   // 3,145,728 B
  u16* wXdB   = (u16*)((char*)bufC + 3670016);  // 98,304 B
  u16* y2t    = bufF;
  u16* out1T  = lnA;
  u16* y4T    = (u16*)bufD;

  cvt_w<<<dim3(2304, 3), 256, 0, stream>>>(win, wInB, wout, wOutB, wprj, wPrjB);
  ln_k<<<4096, 256, 0, stream>>>(hs, nw, nb, lnA, shortcut);
  gemm_bf16<<<dim3(32, 12), 256, 0, stream>>>(wInB, lnA, bufC, 0);            // in_proj -> y1 [b][o][p]
  dwconv7_k<<<3072, 256, 0, stream>>>(bufC, c7w, c7b, bufD);                  // y2 f32
  transpose_f2b<<<dim3(16, 12, 4), 256, 0, stream>>>(bufD, y2t);              // y2 -> token-major bf16
  wcat_k<<<768, 256, 0, stream>>>(wupw, lupw, uupw, dcow, wB);                // gathered scan weights
  cvt_xd<<<192, 256, 0, stream>>>(xdw, wXdB);                                 // xdown weights, padded
  gemm_bf16<<<dim3(32, 1), 256, 0, stream>>>(wXdB, y2t, (float*)xpA, 2);      // xdown -> xpA (q-ordered)
  scan_k<<<3072, 256, 0, stream>>>(bufD, xpA, wB, mww, bufF);                 // out1 bf16 [b][c][p]
  transpose_bf16<<<dim3(16, 12, 4), 256, 0, stream>>>(bufF, out1T);           // -> [pg][c]
  gemm_bf16<<<dim3(32, 12), 256, 0, stream>>>(wOutB, out1T, bufC, 0);         // outconv -> y3 [b][o][p]
  dwconv3_k<<<3072, 256, 0, stream>>>(bufC, odw, bufF);                       // dw3 + x*relu(x) -> bf16
  transpose_bf16<<<dim3(16, 12, 4), 256, 0, stream>>>(bufF, y4T);             // -> [pg][c]
  gemm_bf16<<<dim3(32, 12), 256, 0, stream>>>(wPrjB, y4T, out0, 1);           // outproj -> out [b][t][d]
}

// Round 4
// 279.158 us; speedup vs baseline: 1.6797x; 1.0400x over previous
//
#include <hip/hip_runtime.h>

typedef unsigned short u16;
typedef unsigned int u32;
typedef __attribute__((ext_vector_type(8))) short short8v;   // 8 x bf16 (raw bits)
typedef __attribute__((ext_vector_type(4))) float f32x4;

#define DD 768
#define PP 1024
#define NTOK 4096
#define AS2 544   // act row stride (u16): 512 + 32 -> row stride = 16 banks; adjacent-k rows
                  // land on disjoint bank halves => phase-B 64-lane u16 reads are 2-way (free)

__device__ __forceinline__ u16 f2bf(float f) {
  u32 u = __builtin_bit_cast(u32, f);
  u += 0x7fffu + ((u >> 16) & 1u);
  return (u16)(u >> 16);
}
__device__ __forceinline__ float b2f(u16 v) {
  return __builtin_bit_cast(float, (u32)v << 16);
}

// ---------------- weight f32 -> bf16 (3 matrices of 589824) ----------------
__global__ __launch_bounds__(256) void cvt_w(const float* __restrict__ a, u16* __restrict__ oa,
                                             const float* __restrict__ b, u16* __restrict__ ob,
                                             const float* __restrict__ c, u16* __restrict__ oc) {
  const int i = blockIdx.x * 256 + threadIdx.x;
  const int m = blockIdx.y;
  const float* s = (m == 0) ? a : (m == 1) ? b : c;
  u16* d = (m == 0) ? oa : (m == 1) ? ob : oc;
  d[i] = f2bf(s[i]);
}

// ---------------- xdown weight -> bf16, padded 48x768 -> 64x768 (rows 48+ zero) ----------------
__global__ __launch_bounds__(256) void cvt_xd(const float* __restrict__ w, u16* __restrict__ o) {
  const int i = blockIdx.x * 256 + threadIdx.x;   // 64*768 = 49152
  const int r = i / DD;
  o[i] = (r < 48) ? f2bf(w[i]) : (u16)0;
}

// ---------------- gather scan weights: wB[c][32 rows][64 k] bf16, zero-padded ----------------
// row = type*4 + k ; type in {Gl,Gm,Gr,L,U,D}; rows 24..31 zero, cols 48..63 zero
__global__ __launch_bounds__(256) void wcat_k(const float* __restrict__ wup,
                                              const float* __restrict__ lup,
                                              const float* __restrict__ uup,
                                              const float* __restrict__ dco,
                                              u16* __restrict__ wB) {
  const int c = blockIdx.x;
  const int t = threadIdx.x;
  u16* dst = wB + (size_t)c * 2048;
  for (int i = t; i < 2048; i += 256) {
    const int row = i >> 6, s = i & 63;
    u16 v = 0;
    if (row < 24 && s < 48) {
      const int k = row & 3, type = row >> 2;
      const int ch = k * DD + c;
      const float* src;
      if (type < 3) src = wup + ((size_t)(type * 3072 + ch)) * 48;
      else if (type == 3) src = lup + (size_t)ch * 48;
      else if (type == 4) src = uup + (size_t)ch * 48;
      else src = dco + (size_t)ch * 48;
      v = f2bf(src[s]);
    }
    dst[i] = v;
  }
}

// ---------------- LayerNorm + shortcut copy ----------------
__global__ __launch_bounds__(256) void ln_k(const float* __restrict__ x,
                                            const float* __restrict__ gw, const float* __restrict__ gb,
                                            u16* __restrict__ lnout, float* __restrict__ shortcut) {
  const int tok = blockIdx.x;
  const int t = threadIdx.x;
  const float* xr = x + (size_t)tok * DD;
  float v0 = xr[t], v1 = xr[t + 256], v2 = xr[t + 512];
  float s = v0 + v1 + v2;
  float q = v0 * v0 + v1 * v1 + v2 * v2;
#pragma unroll
  for (int off = 32; off > 0; off >>= 1) {
    s += __shfl_down(s, off, 64);
    q += __shfl_down(q, off, 64);
  }
  __shared__ float ss[4], qs[4];
  const int wid = t >> 6, lane = t & 63;
  if (lane == 0) { ss[wid] = s; qs[wid] = q; }
  __syncthreads();
  const float st = ss[0] + ss[1] + ss[2] + ss[3];
  const float qt = qs[0] + qs[1] + qs[2] + qs[3];
  const float mu = st * (1.f / 768.f);
  const float var = qt * (1.f / 768.f) - mu * mu;
  const float rstd = rsqrtf(var + 1e-5f);
  float* sc = shortcut + (size_t)tok * DD;
  u16* lo = lnout + (size_t)tok * DD;
  sc[t] = v0; sc[t + 256] = v1; sc[t + 512] = v2;
  lo[t]       = f2bf((v0 - mu) * rstd * gw[t] + gb[t]);
  lo[t + 256] = f2bf((v1 - mu) * rstd * gw[t + 256] + gb[t + 256]);
  lo[t + 512] = f2bf((v2 - mu) * rstd * gw[t + 512] + gb[t + 512]);
}

// ---------------- bf16 MFMA GEMM: out[o,pg] = sum_c A[o,c]*Bt[pg,c] ----------------
// A: [M x 768] bf16 row-major;  Bt: 4096x768 bf16 token-major
// mode 0: store f32 channel-major out[(b*768+o)*1024 + p]
// mode 1: store f32 token-major   out[pg*768 + o]
// mode 2: store bf16 to xpA[(b*1024 + q)*64 + o], q = (p&31)*32 + (p>>5)
__global__ __launch_bounds__(256) void gemm_bf16(const u16* __restrict__ A,
                                                 const u16* __restrict__ Bt,
                                                 float* __restrict__ out, const int mode) {
  __shared__ u16 Al[64][40];
  __shared__ u16 Bl[128][40];
  const int t = threadIdx.x;
  const int ntile = blockIdx.x * 128;
  const int mtile = blockIdx.y * 64;
  const int wid = t >> 6, lane = t & 63;
  const int m0 = (wid & 1) * 32, n0 = (wid >> 1) * 64;
  const int l15 = lane & 15, quad = lane >> 4;
  f32x4 acc[2][4];
#pragma unroll
  for (int mi = 0; mi < 2; ++mi)
#pragma unroll
    for (int ni = 0; ni < 4; ++ni) acc[mi][ni] = (f32x4){0.f, 0.f, 0.f, 0.f};
  const int ra = t >> 2, sa = t & 3;
  const int rb = t >> 1, hb = t & 1;
  const u16* ag = A + (size_t)(mtile + ra) * DD + sa * 8;
  const u16* bg = Bt + (size_t)(ntile + rb) * DD + hb * 16;
  for (int k0 = 0; k0 < DD; k0 += 32) {
    const uint4 av = *reinterpret_cast<const uint4*>(ag + k0);
    const uint4 bv0 = *reinterpret_cast<const uint4*>(bg + k0);
    const uint4 bv1 = *reinterpret_cast<const uint4*>(bg + k0 + 8);
    __syncthreads();
    *reinterpret_cast<uint4*>(&Al[ra][sa * 8]) = av;
    *reinterpret_cast<uint4*>(&Bl[rb][hb * 16]) = bv0;
    *reinterpret_cast<uint4*>(&Bl[rb][hb * 16 + 8]) = bv1;
    __syncthreads();
    short8v af[2];
#pragma unroll
    for (int mi = 0; mi < 2; ++mi)
      af[mi] = *reinterpret_cast<const short8v*>(&Al[m0 + mi * 16 + l15][quad * 8]);
    short8v bfr[4];
#pragma unroll
    for (int ni = 0; ni < 4; ++ni)
      bfr[ni] = *reinterpret_cast<const short8v*>(&Bl[n0 + ni * 16 + l15][quad * 8]);
#pragma unroll
    for (int mi = 0; mi < 2; ++mi)
#pragma unroll
      for (int ni = 0; ni < 4; ++ni)
        acc[mi][ni] = __builtin_amdgcn_mfma_f32_16x16x32_bf16(af[mi], bfr[ni], acc[mi][ni], 0, 0, 0);
  }
#pragma unroll
  for (int mi = 0; mi < 2; ++mi) {
#pragma unroll
    for (int ni = 0; ni < 4; ++ni) {
      const int ob = mtile + m0 + mi * 16 + quad * 4;
      const int pg = ntile + n0 + ni * 16 + l15;
      if (mode == 0) {
        const int bb = pg >> 10, pq = pg & 1023;
#pragma unroll
        for (int r = 0; r < 4; ++r)
          out[((size_t)(bb * DD + ob + r)) * PP + pq] = acc[mi][ni][r];
      } else if (mode == 1) {
        *reinterpret_cast<f32x4*>(out + (size_t)pg * DD + ob) = acc[mi][ni];
      } else {
        const int bb = pg >> 10, pq = pg & 1023;
        const int q = (pq & 31) * 32 + (pq >> 5);
        u16* dst = (u16*)out + ((size_t)(bb * 1024 + q)) * 64 + ob;
        const u32 lo = (u32)f2bf(acc[mi][ni][0]) | ((u32)f2bf(acc[mi][ni][1]) << 16);
        const u32 hi = (u32)f2bf(acc[mi][ni][2]) | ((u32)f2bf(acc[mi][ni][3]) << 16);
        *reinterpret_cast<uint2*>(dst) = make_uint2(lo, hi);
      }
    }
  }
}

// ---------------- depthwise 7x7 + bias, f32 -> f32 ----------------
__global__ __launch_bounds__(256) void dwconv7_k(const float* __restrict__ x,
                                                 const float* __restrict__ wgt,
                                                 const float* __restrict__ bias,
                                                 float* __restrict__ y) {
  const int bc = blockIdx.x;
  const int c = bc % DD;
  __shared__ float tile[38 * 38];
  __shared__ float wl[49];
  __shared__ float bsh[1];
  const int t = threadIdx.x;
  for (int i = t; i < 38 * 38; i += 256) tile[i] = 0.f;
  __syncthreads();
  const float* xr = x + (size_t)bc * PP;
  for (int i = t; i < 1024; i += 256) tile[((i >> 5) + 3) * 38 + (i & 31) + 3] = xr[i];
  if (t < 49) wl[t] = wgt[c * 49 + t];
  if (t == 0) bsh[0] = bias[c];
  __syncthreads();
  float* yo = y + (size_t)bc * PP;
  for (int i = t; i < 1024; i += 256) {
    const int h = i >> 5, w = i & 31;
    float acc = bsh[0];
#pragma unroll
    for (int kh = 0; kh < 7; ++kh)
#pragma unroll
      for (int kw = 0; kw < 7; ++kw)
        acc = fmaf(wl[kh * 7 + kw], tile[(h + kh) * 38 + (w + kw)], acc);
    yo[i] = acc;
  }
}

// ---------------- depthwise 3x3 (no bias) + x*relu(x), f32 -> bf16 ----------------
__global__ __launch_bounds__(256) void dwconv3_k(const float* __restrict__ x,
                                                 const float* __restrict__ wgt,
                                                 u16* __restrict__ y) {
  const int bc = blockIdx.x;
  const int c = bc % DD;
  __shared__ float tile[34 * 34];
  __shared__ float wl[9];
  const int t = threadIdx.x;
  for (int i = t; i < 34 * 34; i += 256) tile[i] = 0.f;
  __syncthreads();
  const float* xr = x + (size_t)bc * PP;
  for (int i = t; i < 1024; i += 256) tile[((i >> 5) + 1) * 34 + (i & 31) + 1] = xr[i];
  if (t < 9) wl[t] = wgt[c * 9 + t];
  __syncthreads();
  u16* yo = y + (size_t)bc * PP;
  for (int i = t; i < 1024; i += 256) {
    const int h = i >> 5, w = i & 31;
    float acc = 0.f;
#pragma unroll
    for (int kh = 0; kh < 3; ++kh)
#pragma unroll
      for (int kw = 0; kw < 3; ++kw)
        acc = fmaf(wl[kh * 3 + kw], tile[(h + kh) * 34 + (w + kw)], acc);
    const float r = acc > 0.f ? acc * acc : 0.f;
    yo[i] = f2bf(r);
  }
}

// ---------------- fused MFMA projections + 4-direction chunked scan + recombine ----------------
// grid = 6144: blockIdx.x = bc*2 + half; half selects nc-pair {0,1} / {2,3} (w in [half*16, half*16+16)).
// Chunks (nc) are scan-independent, so each block handles 512 pixels with 34.5 KB LDS -> 4 blocks/CU.
// Phase A: MFMA [512 q x 48] * [48 x 24] -> act bf16 in LDS (q = w_local*32 + h).
// Phase B: wave wid = (nc_local<<1)|dpair; lane = d*32 + h; each lane owns ONE direction k=dpair*2+d.
__global__ __launch_bounds__(256) void scan_k(const float* __restrict__ y2,
                                              const u16* __restrict__ xpA,
                                              const u16* __restrict__ wB,
                                              const float* __restrict__ mwp,
                                              u16* __restrict__ out1) {
  const int bid = blockIdx.x;
  const int bc = bid >> 1;
  const int half = bid & 1;
  const int b = bc / DD;
  const int c = bc - b * DD;
  __shared__ u16 act[24 * AS2];       // 26,112 B
  __shared__ float plane[32][33];     //  4,224 B
  __shared__ float outp[2][16][33];   //  4,224 B
  const int t = threadIdx.x;
  const int wid = t >> 6, lane = t & 63, l15 = lane & 15, quad = lane >> 4;
  {
    const float* yp = y2 + (size_t)bc * PP;
    for (int i = t; i < 1024; i += 256) plane[i >> 5][i & 31] = yp[i];
  }
  // ---- phase A: projections via MFMA (512 q-rows, 128 per wave) ----
  {
    const u16* wc = wB + (size_t)c * 2048;
    short8v bw[2][2];
#pragma unroll
    for (int nt = 0; nt < 2; ++nt)
#pragma unroll
      for (int ks = 0; ks < 2; ++ks)
        bw[nt][ks] = *reinterpret_cast<const short8v*>(wc + (nt * 16 + l15) * 64 + ks * 32 + quad * 8);
    const u16* ab = xpA + ((size_t)(b * 1024 + half * 512 + wid * 128)) * 64;
#pragma unroll 4
    for (int mt = 0; mt < 8; ++mt) {
      const u16* ar = ab + (mt * 16 + l15) * 64 + quad * 8;
      const short8v a0 = *reinterpret_cast<const short8v*>(ar);
      const short8v a1 = *reinterpret_cast<const short8v*>(ar + 32);
      f32x4 acc0 = {0.f, 0.f, 0.f, 0.f}, acc1 = {0.f, 0.f, 0.f, 0.f};
      acc0 = __builtin_amdgcn_mfma_f32_16x16x32_bf16(a0, bw[0][0], acc0, 0, 0, 0);
      acc0 = __builtin_amdgcn_mfma_f32_16x16x32_bf16(a1, bw[0][1], acc0, 0, 0, 0);
      acc1 = __builtin_amdgcn_mfma_f32_16x16x32_bf16(a0, bw[1][0], acc1, 0, 0, 0);
      acc1 = __builtin_amdgcn_mfma_f32_16x16x32_bf16(a1, bw[1][1], acc1, 0, 0, 0);
      const int qb = wid * 128 + mt * 16 + quad * 4;   // D: row(q) = quad*4+reg, col(coef) = l15
      const u32 lo0 = (u32)f2bf(acc0[0]) | ((u32)f2bf(acc0[1]) << 16);
      const u32 hi0 = (u32)f2bf(acc0[2]) | ((u32)f2bf(acc0[3]) << 16);
      *reinterpret_cast<uint2*>(&act[l15 * AS2 + qb]) = make_uint2(lo0, hi0);
      if (l15 < 8) {
        const u32 lo1 = (u32)f2bf(acc1[0]) | ((u32)f2bf(acc1[1]) << 16);
        const u32 hi1 = (u32)f2bf(acc1[2]) | ((u32)f2bf(acc1[3]) << 16);
        *reinterpret_cast<uint2*>(&act[(16 + l15) * AS2 + qb]) = make_uint2(lo1, hi1);
      }
    }
  }
  __syncthreads();
  // ---- phase B: chunked scan, one direction per lane ----
  const int dpair = wid & 1;      // 0: dirs {0,1}, 1: dirs {2,3}   (wave-uniform)
  const int ncl = wid >> 1;       // local chunk 0/1
  const int d = lane >> 5;        // direction within pair
  const int h = lane & 31;
  const int k = dpair * 2 + d;
  const float mw = mwp[k];
  const int rowbase = k * AS2;
  float H = 0.f;
#pragma unroll 1
  for (int j = 0; j < 8; ++j) {
    const int wl = ncl * 8 + j;              // w_local in [0,16)
    const int w = half * 16 + wl;            // global w
    const int qj = wl * 32 + h;
    const int base = rowbase + qj;
    const float aGl = b2f(act[base]);
    const float aGm = b2f(act[base + 4 * AS2]);
    const float aGr = b2f(act[base + 8 * AS2]);
    const float aL  = b2f(act[base + 12 * AS2]);
    const float aU  = b2f(act[base + 16 * AS2]);
    const float aD  = b2f(act[base + 20 * AS2]);
    float gl = 1.f / (1.f + __expf(-aGl));
    float gm = 1.f / (1.f + __expf(-aGm));
    float gr = 1.f / (1.f + __expf(-aGr));
    float s = (h == 0) ? (gm + gr) : ((h == 31) ? (gl + gm) : (gl + gm + gr));
    s = fmaxf(s, 1e-7f);
    const float inv = 1.f / s;
    gl *= inv; gm *= inv; gr *= inv;
    const int wc_ = dpair ? (31 - w) : w;                    // w-flip for dirs 2,3
    const float xv = (d == 0) ? plane[h][wc_] : plane[wc_][h];  // transpose for dirs 1,3
    float up = __shfl(H, lane - 1, 64);
    float dn = __shfl(H, lane + 1, 64);
    if (h == 0) up = 0.f;
    if (h == 31) dn = 0.f;
    H = aL * xv + gl * up + gm * H + gr * dn;
    float part = mw * (H * aU + xv * aD);
    part += __shfl_xor(part, 32, 64);        // combine the direction pair
    if (d == 0) outp[dpair][wl][h] = part;
  }
  __syncthreads();
  const int hh = t >> 3, wp = t & 7;
  const float v0 = outp[0][wp * 2][hh] + outp[1][wp * 2][hh];
  const float v1 = outp[0][wp * 2 + 1][hh] + outp[1][wp * 2 + 1][hh];
  const u32 pk = (u32)f2bf(v0) | ((u32)f2bf(v1) << 16);
  *reinterpret_cast<u32*>(out1 + (size_t)bc * PP + hh * 32 + half * 16 + wp * 2) = pk;
}

// ---------------- bf16 transpose: [b][c][p] -> [(b*1024+p)][c] ----------------
__global__ __launch_bounds__(256) void transpose_bf16(const u16* __restrict__ in,
                                                      u16* __restrict__ out) {
  __shared__ u16 tile[64][72];
  const int b = blockIdx.z;
  const int c0 = blockIdx.y * 64;
  const int p0 = blockIdx.x * 64;
  const int t = threadIdx.x;
  const int r = t >> 2, s2 = t & 3;
  const u16* src = in + ((size_t)(b * DD + c0 + r)) * PP + p0 + s2 * 16;
  *reinterpret_cast<uint4*>(&tile[r][s2 * 16]) = *reinterpret_cast<const uint4*>(src);
  *reinterpret_cast<uint4*>(&tile[r][s2 * 16 + 8]) = *reinterpret_cast<const uint4*>(src + 8);
  __syncthreads();
  const int pr = t >> 2, cs = t & 3;
  union { u16 u[16]; uint4 v[2]; } vals;
#pragma unroll
  for (int i = 0; i < 16; ++i) vals.u[i] = tile[cs * 16 + i][pr];
  u16* dst = out + ((size_t)(b * 1024 + p0 + pr)) * DD + c0 + cs * 16;
  reinterpret_cast<uint4*>(dst)[0] = vals.v[0];
  reinterpret_cast<uint4*>(dst)[1] = vals.v[1];
}

// ---------------- f32 [b][c][p] -> bf16 token-major [(b*1024+p)][c] ----------------
__global__ __launch_bounds__(256) void transpose_f2b(const float* __restrict__ in,
                                                     u16* __restrict__ out) {
  __shared__ u16 tile[64][72];
  const int b = blockIdx.z;
  const int c0 = blockIdx.y * 64;
  const int p0 = blockIdx.x * 64;
  const int t = threadIdx.x;
  const int r = t >> 2, s2 = t & 3;
  const float* src = in + ((size_t)(b * DD + c0 + r)) * PP + p0 + s2 * 16;
  u16* td = &tile[r][s2 * 16];
#pragma unroll
  for (int q = 0; q < 4; ++q) {
    const float4 v = reinterpret_cast<const float4*>(src)[q];
    td[q * 4 + 0] = f2bf(v.x); td[q * 4 + 1] = f2bf(v.y);
    td[q * 4 + 2] = f2bf(v.z); td[q * 4 + 3] = f2bf(v.w);
  }
  __syncthreads();
  const int pr = t >> 2, cs = t & 3;
  union { u16 u[16]; uint4 v[2]; } vals;
#pragma unroll
  for (int i = 0; i < 16; ++i) vals.u[i] = tile[cs * 16 + i][pr];
  u16* dst = out + ((size_t)(b * 1024 + p0 + pr)) * DD + c0 + cs * 16;
  reinterpret_cast<uint4*>(dst)[0] = vals.v[0];
  reinterpret_cast<uint4*>(dst)[1] = vals.v[1];
}

extern "C" void kernel_launch(void* const* d_in, const int* in_sizes, int n_in,
                              void* d_out, int out_size, void* d_ws, size_t ws_size,
                              hipStream_t stream) {
  const float* hs   = (const float*)d_in[0];
  const float* nw   = (const float*)d_in[1];
  const float* nb   = (const float*)d_in[2];
  const float* win  = (const float*)d_in[3];
  const float* c7w  = (const float*)d_in[4];
  const float* c7b  = (const float*)d_in[5];
  const float* xdw  = (const float*)d_in[6];
  const float* wupw = (const float*)d_in[7];
  const float* lupw = (const float*)d_in[8];
  const float* uupw = (const float*)d_in[9];
  const float* dcow = (const float*)d_in[10];
  const float* mww  = (const float*)d_in[11];
  const float* wout = (const float*)d_in[12];
  const float* odw  = (const float*)d_in[13];
  const float* wprj = (const float*)d_in[14];
  float* out0 = (float*)d_out;
  float* shortcut = out0 + (size_t)NTOK * DD;

  char* ws = (char*)d_ws;
  // Slots: A: ln_bf16 (ln..gemm1) then out1_t. C: y1 (gemm1..dw7), then {xpA,wB,wXdB} (..scan), then y3.
  // D: y2 (dw7..scan) then y4_t. F: y2t (transpose_f2b..xdown_gemm) then out1_bf16 then y4_bf16.
  u16* lnA    = (u16*)(ws + 0);           // 6,291,456 B
  u16* wInB   = (u16*)(ws + 6291456);     // 1,179,648 B
  u16* wOutB  = (u16*)(ws + 7471104);     // 1,179,648 B
  u16* wPrjB  = (u16*)(ws + 8650752);     // 1,179,648 B
  float* bufC = (float*)(ws + 9830400);   // 12,582,912 B
  float* bufD = (float*)(ws + 22413312);  // 12,582,912 B
  u16* bufF   = (u16*)(ws + 35782656);    // 6,291,456 B  (total 42,074,112 B)
  u16* xpA    = (u16*)bufC;               // 524,288 B   (alias y1 slot, valid after dwconv7)
  u16* wB     = (u16*)((char*)bufC + 524288);   // 3,145,728 B
  u16* wXdB   = (u16*)((char*)bufC + 3670016);  // 98,304 B
  u16* y2t    = bufF;
  u16* out1T  = lnA;
  u16* y4T    = (u16*)bufD;

  cvt_w<<<dim3(2304, 3), 256, 0, stream>>>(win, wInB, wout, wOutB, wprj, wPrjB);
  ln_k<<<4096, 256, 0, stream>>>(hs, nw, nb, lnA, shortcut);
  gemm_bf16<<<dim3(32, 12), 256, 0, stream>>>(wInB, lnA, bufC, 0);            // in_proj -> y1 [b][o][p]
  dwconv7_k<<<3072, 256, 0, stream>>>(bufC, c7w, c7b, bufD);                  // y2 f32
  transpose_f2b<<<dim3(16, 12, 4), 256, 0, stream>>>(bufD, y2t);              // y2 -> token-major bf16
  wcat_k<<<768, 256, 0, stream>>>(wupw, lupw, uupw, dcow, wB);                // gathered scan weights
  cvt_xd<<<192, 256, 0, stream>>>(xdw, wXdB);                                 // xdown weights, padded
  gemm_bf16<<<dim3(32, 1), 256, 0, stream>>>(wXdB, y2t, (float*)xpA, 2);      // xdown -> xpA (q-ordered)
  scan_k<<<6144, 256, 0, stream>>>(bufD, xpA, wB, mww, bufF);                 // out1 bf16 [b][c][p]
  transpose_bf16<<<dim3(16, 12, 4), 256, 0, stream>>>(bufF, out1T);           // -> [pg][c]
  gemm_bf16<<<dim3(32, 12), 256, 0, stream>>>(wOutB, out1T, bufC, 0);         // outconv -> y3 [b][o][p]
  dwconv3_k<<<3072, 256, 0, stream>>>(bufC, odw, bufF);                       // dw3 + x*relu(x) -> bf16
  transpose_bf16<<<dim3(16, 12, 4), 256, 0, stream>>>(bufF, y4T);             // -> [pg][c]
  gemm_bf16<<<dim3(32, 12), 256, 0, stream>>>(wPrjB, y4T, out0, 1);           // outproj -> out [b][t][d]
}